// Round 4
// baseline (2820.322 us; speedup 1.0000x reference)
//
#include <hip/hip_runtime.h>
#include <hip/hip_bf16.h>
#include <math.h>

#define BNEPS 1e-5f

// =====================================================================
// conv1: 7x7 stride4 pad3, 3->32, fused BN+ReLU
// in : NCHW (256,3,224,224)   out: NHWC (256,56,56,32)
// Each thread: 4 oc x 4 images (n0, n0+64, n0+128, n0+192)
// grid = 784 spatial-blocks * 8 oc-groups, block = 256
// Row loads: ix0 = 4*ox-3. Both ix0-1 = 4(ox-1) and ix0+3 = 4*ox are
// 16B-aligned, so the 7 taps come from TWO aligned float4 loads:
//   head = [ix0-1 .. ix0+2] (only if ox>0; .y/.z/.w used)
//   tail = [ix0+3 .. ix0+6] (always in-bounds; right edge ox=55 -> 220..223)
// Rows with iy<0 (oy==0, ky<3) are skipped; bottom/right never OOB
// (pad=3 < stride=4).
// =====================================================================
__global__ __launch_bounds__(256, 2) void conv1_bn_relu(
    const float* __restrict__ in, const float* __restrict__ w,
    const float* __restrict__ cb, const float* __restrict__ bsc,
    const float* __restrict__ bbi, const float* __restrict__ bmu,
    const float* __restrict__ bva, float* __restrict__ out)
{
    __shared__ float wsm[588]; // [ic][tap][oc4]
    int bs  = blockIdx.x % 784;
    int ocg = blockIdx.x / 784;       // [0,8)
    int tid = threadIdx.x;
    for (int i = tid; i < 588; i += 256) {
        int o = i & 3; int t = i >> 2;
        int ic = t / 49; int tap = t % 49;
        wsm[i] = w[(ocg * 4 + o) * 147 + ic * 49 + tap];
    }
    __syncthreads();

    int sg = bs * 256 + tid;          // [0, 200704)
    int n0 = sg / 3136;               // [0,64)
    int s  = sg - n0 * 3136;
    int oy = s / 56, ox = s - oy * 56;
    int iy0 = oy * 4 - 3, ix0 = ox * 4 - 3;
    bool headok = (ox > 0);

    float acc[4][4];
    #pragma unroll
    for (int i = 0; i < 4; ++i)
        #pragma unroll
        for (int o = 0; o < 4; ++o) acc[i][o] = 0.f;

    const size_t img = (size_t)3 * 224 * 224;
    const float* base0 = in + (size_t)n0 * img;

    for (int ic = 0; ic < 3; ++ic) {
        const float* xc = base0 + (size_t)ic * 224 * 224;
        const float* wc = wsm + ic * 49 * 4;
        #pragma unroll
        for (int ky = 0; ky < 7; ++ky) {
            bool rowok = (ky >= 3) || (oy > 0);
            if (rowok) {
                int iy = iy0 + ky;
                const float* xr = xc + iy * 224;
                float r[4][7];
                #pragma unroll
                for (int i = 0; i < 4; ++i) {
                    const float* xri = xr + (size_t)i * 64 * img;
                    float4 hd = make_float4(0.f, 0.f, 0.f, 0.f);
                    if (headok) hd = *(const float4*)(xri + ix0 - 1); // aligned
                    float4 tl = *(const float4*)(xri + ix0 + 3);      // aligned
                    r[i][0] = hd.y; r[i][1] = hd.z; r[i][2] = hd.w;
                    r[i][3] = tl.x; r[i][4] = tl.y; r[i][5] = tl.z; r[i][6] = tl.w;
                }
                #pragma unroll
                for (int kx = 0; kx < 7; ++kx) {
                    float4 wv = *(const float4*)(wc + (ky * 7 + kx) * 4);
                    float wr[4] = {wv.x, wv.y, wv.z, wv.w};
                    #pragma unroll
                    for (int i = 0; i < 4; ++i)
                        #pragma unroll
                        for (int o = 0; o < 4; ++o)
                            acc[i][o] = fmaf(r[i][kx], wr[o], acc[i][o]);
                }
            }
        }
    }

    // NHWC epilogue: 4 contiguous oc -> one float4 store per image
    float scale[4], shift[4];
    #pragma unroll
    for (int o = 0; o < 4; ++o) {
        int oc = ocg * 4 + o;
        scale[o] = bsc[oc] * rsqrtf(bva[oc] + BNEPS);
        shift[o] = (cb[oc] - bmu[oc]) * scale[o] + bbi[oc];
    }
    #pragma unroll
    for (int i = 0; i < 4; ++i) {
        int n = n0 + 64 * i;
        float4 r;
        r.x = fmaxf(fmaf(acc[i][0], scale[0], shift[0]), 0.f);
        r.y = fmaxf(fmaf(acc[i][1], scale[1], shift[1]), 0.f);
        r.z = fmaxf(fmaf(acc[i][2], scale[2], shift[2]), 0.f);
        r.w = fmaxf(fmaf(acc[i][3], scale[3], shift[3]), 0.f);
        *(float4*)(out + ((size_t)n * 3136 + s) * 32 + ocg * 4) = r;
    }
}

// =====================================================================
// generic 3x3 stride2 pad1 conv, NHWC in / NHWC out, fused BN+ReLU
// Each thread: 8 oc x 4 images.  float4 loads over IC.
// OOB only top/left: ok = ((ky>0)||(oy>0)) && ((kx>0)||(ox>0))
// (4/9 taps compile-time unconditional after unroll)
// =====================================================================
template<int IC, int IH, int IW, int OC, int OH, int OW, int NSB>
__global__ __launch_bounds__(256, 2) void conv3x3_bn_relu_nhwc(
    const float* __restrict__ in, const float* __restrict__ w,
    const float* __restrict__ cb, const float* __restrict__ bsc,
    const float* __restrict__ bbi, const float* __restrict__ bmu,
    const float* __restrict__ bva, float* __restrict__ out)
{
    constexpr int OCPT = 8;
    constexpr int WN = 9 * IC * OCPT;
    __shared__ float wsm[WN];         // [tap][ic][oc8]
    int bs  = blockIdx.x % NSB;
    int ocg = blockIdx.x / NSB;
    int tid = threadIdx.x;
    for (int i = tid; i < WN; i += 256) {
        int o = i & 7; int t = i >> 3;
        int tap = t / IC; int ic = t % IC;
        wsm[i] = w[(size_t)(ocg * OCPT + o) * IC * 9 + ic * 9 + tap];
    }
    __syncthreads();

    int sg = bs * 256 + tid;
    int n0 = sg / (OH * OW);          // [0,64)
    int s  = sg - n0 * (OH * OW);
    int oy = s / OW, ox = s - oy * OW;
    int iy0 = oy * 2 - 1, ix0 = ox * 2 - 1;

    float acc[4][OCPT];
    #pragma unroll
    for (int i = 0; i < 4; ++i)
        #pragma unroll
        for (int o = 0; o < OCPT; ++o) acc[i][o] = 0.f;

    const size_t img = (size_t)IH * IW * IC;   // NHWC elems per image
    const float* base0 = in + (size_t)n0 * img;

    #pragma unroll
    for (int ky = 0; ky < 3; ++ky) {
        #pragma unroll
        for (int kx = 0; kx < 3; ++kx) {
            bool ok = ((ky > 0) || (oy > 0)) && ((kx > 0) || (ox > 0));
            if (ok) {
                int iy = iy0 + ky, ix = ix0 + kx;
                const float* p0 = base0 + ((size_t)iy * IW + ix) * IC;
                const float* wt0 = wsm + (ky * 3 + kx) * IC * OCPT;
                for (int icv = 0; icv < IC / 4; ++icv) {
                    float4 v0 = *(const float4*)(p0 + icv * 4);
                    float4 v1 = *(const float4*)(p0 + icv * 4 + 64 * img);
                    float4 v2 = *(const float4*)(p0 + icv * 4 + 128 * img);
                    float4 v3 = *(const float4*)(p0 + icv * 4 + 192 * img);
                    const float4* wt = (const float4*)(wt0 + icv * 4 * OCPT);
                    float vi[4][4] = {{v0.x, v0.y, v0.z, v0.w},
                                      {v1.x, v1.y, v1.z, v1.w},
                                      {v2.x, v2.y, v2.z, v2.w},
                                      {v3.x, v3.y, v3.z, v3.w}};
                    #pragma unroll
                    for (int c = 0; c < 4; ++c) {
                        float4 wa = wt[c * 2], wb = wt[c * 2 + 1];
                        float wr[8] = {wa.x, wa.y, wa.z, wa.w, wb.x, wb.y, wb.z, wb.w};
                        #pragma unroll
                        for (int i = 0; i < 4; ++i)
                            #pragma unroll
                            for (int o = 0; o < 8; ++o)
                                acc[i][o] = fmaf(vi[i][c], wr[o], acc[i][o]);
                    }
                }
            }
        }
    }

    float scale[OCPT], shift[OCPT];
    #pragma unroll
    for (int o = 0; o < OCPT; ++o) {
        int oc = ocg * OCPT + o;
        scale[o] = bsc[oc] * rsqrtf(bva[oc] + BNEPS);
        shift[o] = (cb[oc] - bmu[oc]) * scale[o] + bbi[oc];
    }
    #pragma unroll
    for (int i = 0; i < 4; ++i) {
        int n = n0 + 64 * i;
        float4 r0, r1;
        r0.x = fmaxf(fmaf(acc[i][0], scale[0], shift[0]), 0.f);
        r0.y = fmaxf(fmaf(acc[i][1], scale[1], shift[1]), 0.f);
        r0.z = fmaxf(fmaf(acc[i][2], scale[2], shift[2]), 0.f);
        r0.w = fmaxf(fmaf(acc[i][3], scale[3], shift[3]), 0.f);
        r1.x = fmaxf(fmaf(acc[i][4], scale[4], shift[4]), 0.f);
        r1.y = fmaxf(fmaf(acc[i][5], scale[5], shift[5]), 0.f);
        r1.z = fmaxf(fmaf(acc[i][6], scale[6], shift[6]), 0.f);
        r1.w = fmaxf(fmaf(acc[i][7], scale[7], shift[7]), 0.f);
        float* op = out + ((size_t)n * (OH * OW) + s) * OC + ocg * OCPT;
        *(float4*)(op)     = r0;
        *(float4*)(op + 4) = r1;
    }
}

// =====================================================================
// avgpool NHWC (256,14,14,128) -> pooled (256,512) in reference feature
// order f = c*4 + py*2 + px
// =====================================================================
__global__ __launch_bounds__(256) void pool_kernel(
    const float* __restrict__ in, float* __restrict__ out)
{
    int i = blockIdx.x * 256 + threadIdx.x;   // 131072 total
    int n = i >> 9; int f = i & 511;
    int c = f >> 2; int py = (f >> 1) & 1; int px = f & 1;
    const float* p = in + (((size_t)n * 14 + py * 7) * 14 + px * 7) * 128 + c;
    float sum = 0.f;
    #pragma unroll
    for (int dy = 0; dy < 7; ++dy)
        #pragma unroll
        for (int dx = 0; dx < 7; ++dx) sum += p[(dy * 14 + dx) * 128];
    out[i] = sum * (1.f / 49.f);
}

// =====================================================================
// head: pre-linear + tanh*pi + 4-qubit statevector sim + post1/post2
// one wave (64 lanes) per image
// =====================================================================
__device__ __forceinline__ void q_ry(float2* st, int q, float t) {
    float s, c; sincosf(0.5f * t, &s, &c);
    int m = 1 << (3 - q);
    #pragma unroll
    for (int i = 0; i < 16; ++i) {
        if (!(i & m)) {
            float2 a0 = st[i], a1 = st[i | m];
            st[i]     = make_float2(c * a0.x - s * a1.x, c * a0.y - s * a1.y);
            st[i | m] = make_float2(s * a0.x + c * a1.x, s * a0.y + c * a1.y);
        }
    }
}
__device__ __forceinline__ void q_rx(float2* st, int q, float t) {
    float s, c; sincosf(0.5f * t, &s, &c);
    int m = 1 << (3 - q);
    #pragma unroll
    for (int i = 0; i < 16; ++i) {
        if (!(i & m)) {
            float2 a0 = st[i], a1 = st[i | m];
            st[i]     = make_float2(c * a0.x + s * a1.y, c * a0.y - s * a1.x);
            st[i | m] = make_float2(s * a0.y + c * a1.x, -s * a0.x + c * a1.y);
        }
    }
}
__device__ __forceinline__ void q_rz(float2* st, int q, float t) {
    float s, c; sincosf(0.5f * t, &s, &c);
    int m = 1 << (3 - q);
    #pragma unroll
    for (int i = 0; i < 16; ++i) {
        float2 a = st[i];
        if (i & m)  st[i] = make_float2(a.x * c - a.y * s, a.y * c + a.x * s);
        else        st[i] = make_float2(a.x * c + a.y * s, a.y * c - a.x * s);
    }
}
__device__ __forceinline__ void q_cnot(float2* st, int c, int t) {
    int mc = 1 << (3 - c), mt = 1 << (3 - t);
    #pragma unroll
    for (int i = 0; i < 16; ++i) {
        if ((i & mc) && !(i & mt)) {
            float2 tmp = st[i]; st[i] = st[i | mt]; st[i | mt] = tmp;
        }
    }
}

__global__ __launch_bounds__(64) void head_kernel(
    const float* __restrict__ h,      // (256,512)
    const float* __restrict__ pre_w, const float* __restrict__ pre_b,
    const float* __restrict__ qw,     // (2,4,3)
    const float* __restrict__ p1w, const float* __restrict__ p1b,
    const float* __restrict__ p2w, const float* __restrict__ p2b,
    float* __restrict__ out)
{
    int n = blockIdx.x;
    int lane = threadIdx.x;
    const float* hb = h + (size_t)n * 512;

    float part[4] = {0.f, 0.f, 0.f, 0.f};
    #pragma unroll
    for (int j = 0; j < 8; ++j) {
        int idx = lane * 8 + j;
        float hv = hb[idx];
        #pragma unroll
        for (int o = 0; o < 4; ++o)
            part[o] = fmaf(hv, pre_w[o * 512 + idx], part[o]);
    }
    #pragma unroll
    for (int o = 0; o < 4; ++o) {
        float p = part[o];
        #pragma unroll
        for (int off = 32; off >= 1; off >>= 1) p += __shfl_xor(p, off);
        part[o] = p;
    }
    float ang[4];
    #pragma unroll
    for (int o = 0; o < 4; ++o)
        ang[o] = tanhf(part[o] + pre_b[o]) * 3.14159265358979323846f;

    // 4-qubit statevector sim (all lanes redundantly; wave-uniform)
    float2 st[16];
    #pragma unroll
    for (int i = 0; i < 16; ++i) st[i] = make_float2(0.f, 0.f);
    st[0] = make_float2(1.f, 0.f);
    #pragma unroll
    for (int q = 0; q < 4; ++q) q_ry(st, q, ang[q]);
    #pragma unroll
    for (int l = 0; l < 2; ++l) {
        #pragma unroll
        for (int q = 0; q < 4; ++q) {
            q_rx(st, q, qw[(l * 4 + q) * 3 + 0]);
            q_ry(st, q, qw[(l * 4 + q) * 3 + 1]);
            q_rz(st, q, qw[(l * 4 + q) * 3 + 2]);
        }
        #pragma unroll
        for (int q = 0; q < 3; ++q) q_cnot(st, q, q + 1);
    }
    float ev[4];
    #pragma unroll
    for (int q = 0; q < 4; ++q) {
        int m = 1 << (3 - q);
        float e = 0.f;
        #pragma unroll
        for (int i = 0; i < 16; ++i) {
            float p = st[i].x * st[i].x + st[i].y * st[i].y;
            e += (i & m) ? -p : p;
        }
        ev[q] = e;
    }

    // post1 row per lane, relu
    float y = p1b[lane];
    #pragma unroll
    for (int o = 0; o < 4; ++o) y = fmaf(ev[o], p1w[lane * 4 + o], y);
    y = fmaxf(y, 0.f);

    // post2: 5 wave reductions
    float o5[5];
    #pragma unroll
    for (int k = 0; k < 5; ++k) {
        float p = y * p2w[k * 64 + lane];
        #pragma unroll
        for (int off = 32; off >= 1; off >>= 1) p += __shfl_xor(p, off);
        o5[k] = p;
    }
    if (lane == 0) {
        #pragma unroll
        for (int k = 0; k < 5; ++k) out[n * 5 + k] = o5[k] + p2b[k];
    }
}

// =====================================================================
extern "C" void kernel_launch(void* const* d_in, const int* in_sizes, int n_in,
                              void* d_out, int out_size, void* d_ws, size_t ws_size,
                              hipStream_t stream)
{
    const float* x   = (const float*)d_in[0];
    const float* c1w = (const float*)d_in[1];
    const float* c1b = (const float*)d_in[2];
    const float* b1s = (const float*)d_in[3];
    const float* b1b = (const float*)d_in[4];
    const float* b1m = (const float*)d_in[5];
    const float* b1v = (const float*)d_in[6];
    const float* c2w = (const float*)d_in[7];
    const float* c2b = (const float*)d_in[8];
    const float* b2s = (const float*)d_in[9];
    const float* b2b = (const float*)d_in[10];
    const float* b2m = (const float*)d_in[11];
    const float* b2v = (const float*)d_in[12];
    const float* c3w = (const float*)d_in[13];
    const float* c3b = (const float*)d_in[14];
    const float* b3s = (const float*)d_in[15];
    const float* b3b = (const float*)d_in[16];
    const float* b3m = (const float*)d_in[17];
    const float* b3v = (const float*)d_in[18];
    const float* prw = (const float*)d_in[19];
    const float* prb = (const float*)d_in[20];
    const float* qw  = (const float*)d_in[21];
    const float* p1w = (const float*)d_in[22];
    const float* p1b = (const float*)d_in[23];
    const float* p2w = (const float*)d_in[24];
    const float* p2b = (const float*)d_in[25];

    float* buf1   = (float*)d_ws;                              // NHWC (256,56,56,32)
    float* buf2   = buf1 + (size_t)256 * 3136 * 32;            // NHWC (256,28,28,64)
    float* buf3   = (float*)d_ws;                              // reuse: NHWC (256,14,14,128)
    float* pooled = buf3 + (size_t)256 * 196 * 128;            // (256,512)
    float* outp   = (float*)d_out;

    // conv1: (256,3,224,224) -> NHWC (256,56,56,32)
    hipLaunchKernelGGL(conv1_bn_relu, dim3(784 * 8), dim3(256), 0, stream,
                       x, c1w, c1b, b1s, b1b, b1m, b1v, buf1);

    // conv2: 32->64, 56->28.  NSB = 256*784/4/256 = 196; ocg = 8
    hipLaunchKernelGGL((conv3x3_bn_relu_nhwc<32, 56, 56, 64, 28, 28, 196>),
                       dim3(196 * 8), dim3(256), 0, stream,
                       buf1, c2w, c2b, b2s, b2b, b2m, b2v, buf2);

    // conv3: 64->128, 28->14.  NSB = 256*196/4/256 = 49; ocg = 16
    hipLaunchKernelGGL((conv3x3_bn_relu_nhwc<64, 28, 28, 128, 14, 14, 49>),
                       dim3(49 * 16), dim3(256), 0, stream,
                       buf2, c3w, c3b, b3s, b3b, b3m, b3v, buf3);

    // pool: NHWC (256,14,14,128) -> (256,512) reference order
    hipLaunchKernelGGL(pool_kernel, dim3(131072 / 256), dim3(256), 0, stream,
                       buf3, pooled);

    // head: one wave per image
    hipLaunchKernelGGL(head_kernel, dim3(256), dim3(64), 0, stream,
                       pooled, prw, prb, qw, p1w, p1b, p2w, p2b, outp);
}

// Round 7
// 970.073 us; speedup vs baseline: 2.9073x; 2.9073x over previous
//
#include <hip/hip_runtime.h>
#include <hip/hip_bf16.h>
#include <math.h>

#define BNEPS 1e-5f

// Chunked XCD swizzle: grid = NSBP*NOCG (NSBP = ceil(NSB/8)*8). hb%8 = XCD
// (round-robin dispatch heuristic). Per XCD: contiguous bs range, with all
// NOCG oc-groups of each bs dispatched consecutively -> input re-reads served
// by that XCD's L2 instead of HBM. Bijective; dead blocks (bs>=NSB) return.
#define XCD_DECODE(NSB_, NSBP_, NOCG_)                 \
    int hb  = blockIdx.x;                              \
    int pos = hb % (8 * (NOCG_));                      \
    int xcd = pos % 8;                                 \
    int ocg = pos / 8;                                 \
    int sg8 = hb / (8 * (NOCG_));                      \
    int bs  = xcd * ((NSBP_) / 8) + sg8;               \
    if (bs >= (NSB_)) return;

// =====================================================================
// conv1: 7x7 stride4 pad3, 3->32, fused BN+ReLU
// in : NCHW (256,3,224,224)   out: NHWC (256,56,56,32)
// Thread: 8 oc x 2 images (n0, n0+128).  NOCG=4, NSB=1568 (%8==0).
// Row loads: ix0=4*ox-3; ix0-1=4(ox-1) and ix0+3=4*ox both 16B-aligned ->
// two aligned float4 per (img,ic,ky): head (ox>0 only; .y/.z/.w) + tail.
// Rows iy<0 (oy==0, ky<3) skipped; bottom/right never OOB (pad<stride).
// =====================================================================
__global__ __launch_bounds__(256, 2) void conv1_bn_relu(
    const float* __restrict__ in, const float* __restrict__ w,
    const float* __restrict__ cb, const float* __restrict__ bsc,
    const float* __restrict__ bbi, const float* __restrict__ bmu,
    const float* __restrict__ bva, float* __restrict__ out)
{
    XCD_DECODE(1568, 1568, 4);
    __shared__ float wsm[1176]; // [ic][tap][oc8]
    int tid = threadIdx.x;
    for (int i = tid; i < 1176; i += 256) {
        int o = i & 7; int t = i >> 3;
        int ic = t / 49; int tap = t % 49;
        wsm[i] = w[(ocg * 8 + o) * 147 + ic * 49 + tap];
    }
    __syncthreads();

    int sg = bs * 256 + tid;          // [0, 401408)
    int n0 = sg / 3136;               // [0,128)
    int s  = sg - n0 * 3136;
    int oy = s / 56, ox = s - oy * 56;
    int iy0 = oy * 4 - 3, ix0 = ox * 4 - 3;
    bool headok = (ox > 0);

    float acc[2][8];
    #pragma unroll
    for (int i = 0; i < 2; ++i)
        #pragma unroll
        for (int o = 0; o < 8; ++o) acc[i][o] = 0.f;

    const size_t img = (size_t)3 * 224 * 224;
    const float* base0 = in + (size_t)n0 * img;

    for (int ic = 0; ic < 3; ++ic) {
        const float* xc = base0 + (size_t)ic * 224 * 224;
        const float* wc = wsm + ic * 49 * 8;
        #pragma unroll
        for (int ky = 0; ky < 7; ++ky) {
            bool rowok = (ky >= 3) || (oy > 0);
            if (rowok) {
                int iy = iy0 + ky;
                const float* xr = xc + iy * 224;
                float r[2][7];
                #pragma unroll
                for (int i = 0; i < 2; ++i) {
                    const float* xri = xr + (size_t)i * 128 * img;
                    float4 hd = make_float4(0.f, 0.f, 0.f, 0.f);
                    if (headok) hd = *(const float4*)(xri + ix0 - 1); // aligned
                    float4 tl = *(const float4*)(xri + ix0 + 3);      // aligned
                    r[i][0] = hd.y; r[i][1] = hd.z; r[i][2] = hd.w;
                    r[i][3] = tl.x; r[i][4] = tl.y; r[i][5] = tl.z; r[i][6] = tl.w;
                }
                #pragma unroll
                for (int kx = 0; kx < 7; ++kx) {
                    const float4* wv = (const float4*)(wc + (ky * 7 + kx) * 8);
                    float4 wa = wv[0], wb = wv[1];
                    float wr[8] = {wa.x, wa.y, wa.z, wa.w, wb.x, wb.y, wb.z, wb.w};
                    #pragma unroll
                    for (int i = 0; i < 2; ++i)
                        #pragma unroll
                        for (int o = 0; o < 8; ++o)
                            acc[i][o] = fmaf(r[i][kx], wr[o], acc[i][o]);
                }
            }
        }
    }

    float scale[8], shift[8];
    #pragma unroll
    for (int o = 0; o < 8; ++o) {
        int oc = ocg * 8 + o;
        scale[o] = bsc[oc] * rsqrtf(bva[oc] + BNEPS);
        shift[o] = (cb[oc] - bmu[oc]) * scale[o] + bbi[oc];
    }
    #pragma unroll
    for (int i = 0; i < 2; ++i) {
        int n = n0 + 128 * i;
        float4 r0, r1;
        r0.x = fmaxf(fmaf(acc[i][0], scale[0], shift[0]), 0.f);
        r0.y = fmaxf(fmaf(acc[i][1], scale[1], shift[1]), 0.f);
        r0.z = fmaxf(fmaf(acc[i][2], scale[2], shift[2]), 0.f);
        r0.w = fmaxf(fmaf(acc[i][3], scale[3], shift[3]), 0.f);
        r1.x = fmaxf(fmaf(acc[i][4], scale[4], shift[4]), 0.f);
        r1.y = fmaxf(fmaf(acc[i][5], scale[5], shift[5]), 0.f);
        r1.z = fmaxf(fmaf(acc[i][6], scale[6], shift[6]), 0.f);
        r1.w = fmaxf(fmaf(acc[i][7], scale[7], shift[7]), 0.f);
        float* op = out + ((size_t)n * 3136 + s) * 32 + ocg * 8;
        *(float4*)(op)     = r0;
        *(float4*)(op + 4) = r1;
    }
}

// =====================================================================
// generic 3x3 stride2 pad1 conv, NHWC in / NHWC out, fused BN+ReLU
// Thread: 16 oc x 2 images (n0, n0+128).  float4 loads over IC.
// OOB only top/left: ok = ((ky>0)||(oy>0)) && ((kx>0)||(ox>0))
// =====================================================================
template<int IC, int IH, int IW, int OC, int OH, int OW, int NSB, int NSBP, int NOCG>
__global__ __launch_bounds__(256, 2) void conv3x3_bn_relu_nhwc(
    const float* __restrict__ in, const float* __restrict__ w,
    const float* __restrict__ cb, const float* __restrict__ bsc,
    const float* __restrict__ bbi, const float* __restrict__ bmu,
    const float* __restrict__ bva, float* __restrict__ out)
{
    constexpr int OCPT = 16;
    constexpr int WN = 9 * IC * OCPT;
    XCD_DECODE(NSB, NSBP, NOCG);
    __shared__ float wsm[WN];         // [tap][ic][oc16]
    int tid = threadIdx.x;
    for (int i = tid; i < WN; i += 256) {
        int o = i & 15; int t = i >> 4;
        int tap = t / IC; int ic = t % IC;
        wsm[i] = w[(size_t)(ocg * OCPT + o) * IC * 9 + ic * 9 + tap];
    }
    __syncthreads();

    int sg = bs * 256 + tid;
    int n0 = sg / (OH * OW);          // [0,128)
    int s  = sg - n0 * (OH * OW);
    int oy = s / OW, ox = s - oy * OW;
    int iy0 = oy * 2 - 1, ix0 = ox * 2 - 1;

    float acc[2][OCPT];
    #pragma unroll
    for (int i = 0; i < 2; ++i)
        #pragma unroll
        for (int o = 0; o < OCPT; ++o) acc[i][o] = 0.f;

    const size_t img = (size_t)IH * IW * IC;   // NHWC elems per image
    const float* base0 = in + (size_t)n0 * img;

    #pragma unroll
    for (int ky = 0; ky < 3; ++ky) {
        #pragma unroll
        for (int kx = 0; kx < 3; ++kx) {
            bool ok = ((ky > 0) || (oy > 0)) && ((kx > 0) || (ox > 0));
            if (ok) {
                int iy = iy0 + ky, ix = ix0 + kx;
                const float* p0 = base0 + ((size_t)iy * IW + ix) * IC;
                const float* wt0 = wsm + (ky * 3 + kx) * IC * OCPT;
                for (int icv = 0; icv < IC / 4; ++icv) {
                    float4 v0 = *(const float4*)(p0 + icv * 4);
                    float4 v1 = *(const float4*)(p0 + icv * 4 + 128 * img);
                    float va[4] = {v0.x, v0.y, v0.z, v0.w};
                    float vb[4] = {v1.x, v1.y, v1.z, v1.w};
                    #pragma unroll
                    for (int c = 0; c < 4; ++c) {
                        const float4* wt = (const float4*)(wt0 + (icv * 4 + c) * OCPT);
                        float4 w0 = wt[0], w1 = wt[1], w2 = wt[2], w3 = wt[3];
                        float wr[16] = {w0.x, w0.y, w0.z, w0.w, w1.x, w1.y, w1.z, w1.w,
                                        w2.x, w2.y, w2.z, w2.w, w3.x, w3.y, w3.z, w3.w};
                        #pragma unroll
                        for (int o = 0; o < 16; ++o) {
                            acc[0][o] = fmaf(va[c], wr[o], acc[0][o]);
                            acc[1][o] = fmaf(vb[c], wr[o], acc[1][o]);
                        }
                    }
                }
            }
        }
    }

    float scale[OCPT], shift[OCPT];
    #pragma unroll
    for (int o = 0; o < OCPT; ++o) {
        int oc = ocg * OCPT + o;
        scale[o] = bsc[oc] * rsqrtf(bva[oc] + BNEPS);
        shift[o] = (cb[oc] - bmu[oc]) * scale[o] + bbi[oc];
    }
    #pragma unroll
    for (int i = 0; i < 2; ++i) {
        int n = n0 + 128 * i;
        float* op = out + ((size_t)n * (OH * OW) + s) * OC + ocg * OCPT;
        #pragma unroll
        for (int v = 0; v < 4; ++v) {
            float4 r;
            r.x = fmaxf(fmaf(acc[i][v * 4 + 0], scale[v * 4 + 0], shift[v * 4 + 0]), 0.f);
            r.y = fmaxf(fmaf(acc[i][v * 4 + 1], scale[v * 4 + 1], shift[v * 4 + 1]), 0.f);
            r.z = fmaxf(fmaf(acc[i][v * 4 + 2], scale[v * 4 + 2], shift[v * 4 + 2]), 0.f);
            r.w = fmaxf(fmaf(acc[i][v * 4 + 3], scale[v * 4 + 3], shift[v * 4 + 3]), 0.f);
            *(float4*)(op + v * 4) = r;
        }
    }
}

// =====================================================================
// avgpool NHWC (256,14,14,128) -> pooled (256,512), f = c*4 + py*2 + px
// =====================================================================
__global__ __launch_bounds__(256) void pool_kernel(
    const float* __restrict__ in, float* __restrict__ out)
{
    int i = blockIdx.x * 256 + threadIdx.x;   // 131072 total
    int n = i >> 9; int f = i & 511;
    int c = f >> 2; int py = (f >> 1) & 1; int px = f & 1;
    const float* p = in + (((size_t)n * 14 + py * 7) * 14 + px * 7) * 128 + c;
    float sum = 0.f;
    #pragma unroll
    for (int dy = 0; dy < 7; ++dy)
        #pragma unroll
        for (int dx = 0; dx < 7; ++dx) sum += p[(dy * 14 + dx) * 128];
    out[i] = sum * (1.f / 49.f);
}

// =====================================================================
// head: pre-linear + tanh*pi + 4-qubit statevector sim + post1/post2
// one wave (64 lanes) per image
// =====================================================================
__device__ __forceinline__ void q_ry(float2* st, int q, float t) {
    float s, c; sincosf(0.5f * t, &s, &c);
    int m = 1 << (3 - q);
    #pragma unroll
    for (int i = 0; i < 16; ++i) {
        if (!(i & m)) {
            float2 a0 = st[i], a1 = st[i | m];
            st[i]     = make_float2(c * a0.x - s * a1.x, c * a0.y - s * a1.y);
            st[i | m] = make_float2(s * a0.x + c * a1.x, s * a0.y + c * a1.y);
        }
    }
}
__device__ __forceinline__ void q_rx(float2* st, int q, float t) {
    float s, c; sincosf(0.5f * t, &s, &c);
    int m = 1 << (3 - q);
    #pragma unroll
    for (int i = 0; i < 16; ++i) {
        if (!(i & m)) {
            float2 a0 = st[i], a1 = st[i | m];
            st[i]     = make_float2(c * a0.x + s * a1.y, c * a0.y - s * a1.x);
            st[i | m] = make_float2(s * a0.y + c * a1.x, -s * a0.x + c * a1.y);
        }
    }
}
__device__ __forceinline__ void q_rz(float2* st, int q, float t) {
    float s, c; sincosf(0.5f * t, &s, &c);
    int m = 1 << (3 - q);
    #pragma unroll
    for (int i = 0; i < 16; ++i) {
        float2 a = st[i];
        if (i & m)  st[i] = make_float2(a.x * c - a.y * s, a.y * c + a.x * s);
        else        st[i] = make_float2(a.x * c + a.y * s, a.y * c - a.x * s);
    }
}
__device__ __forceinline__ void q_cnot(float2* st, int c, int t) {
    int mc = 1 << (3 - c), mt = 1 << (3 - t);
    #pragma unroll
    for (int i = 0; i < 16; ++i) {
        if ((i & mc) && !(i & mt)) {
            float2 tmp = st[i]; st[i] = st[i | mt]; st[i | mt] = tmp;
        }
    }
}

__global__ __launch_bounds__(64) void head_kernel(
    const float* __restrict__ h,      // (256,512)
    const float* __restrict__ pre_w, const float* __restrict__ pre_b,
    const float* __restrict__ qw,     // (2,4,3)
    const float* __restrict__ p1w, const float* __restrict__ p1b,
    const float* __restrict__ p2w, const float* __restrict__ p2b,
    float* __restrict__ out)
{
    int n = blockIdx.x;
    int lane = threadIdx.x;
    const float* hb = h + (size_t)n * 512;

    float part[4] = {0.f, 0.f, 0.f, 0.f};
    #pragma unroll
    for (int j = 0; j < 8; ++j) {
        int idx = lane * 8 + j;
        float hv = hb[idx];
        #pragma unroll
        for (int o = 0; o < 4; ++o)
            part[o] = fmaf(hv, pre_w[o * 512 + idx], part[o]);
    }
    #pragma unroll
    for (int o = 0; o < 4; ++o) {
        float p = part[o];
        #pragma unroll
        for (int off = 32; off >= 1; off >>= 1) p += __shfl_xor(p, off);
        part[o] = p;
    }
    float ang[4];
    #pragma unroll
    for (int o = 0; o < 4; ++o)
        ang[o] = tanhf(part[o] + pre_b[o]) * 3.14159265358979323846f;

    // 4-qubit statevector sim (all lanes redundantly; wave-uniform)
    float2 st[16];
    #pragma unroll
    for (int i = 0; i < 16; ++i) st[i] = make_float2(0.f, 0.f);
    st[0] = make_float2(1.f, 0.f);
    #pragma unroll
    for (int q = 0; q < 4; ++q) q_ry(st, q, ang[q]);
    #pragma unroll
    for (int l = 0; l < 2; ++l) {
        #pragma unroll
        for (int q = 0; q < 4; ++q) {
            q_rx(st, q, qw[(l * 4 + q) * 3 + 0]);
            q_ry(st, q, qw[(l * 4 + q) * 3 + 1]);
            q_rz(st, q, qw[(l * 4 + q) * 3 + 2]);
        }
        #pragma unroll
        for (int q = 0; q < 3; ++q) q_cnot(st, q, q + 1);
    }
    float ev[4];
    #pragma unroll
    for (int q = 0; q < 4; ++q) {
        int m = 1 << (3 - q);
        float e = 0.f;
        #pragma unroll
        for (int i = 0; i < 16; ++i) {
            float p = st[i].x * st[i].x + st[i].y * st[i].y;
            e += (i & m) ? -p : p;
        }
        ev[q] = e;
    }

    // post1 row per lane, relu
    float y = p1b[lane];
    #pragma unroll
    for (int o = 0; o < 4; ++o) y = fmaf(ev[o], p1w[lane * 4 + o], y);
    y = fmaxf(y, 0.f);

    // post2: 5 wave reductions
    float o5[5];
    #pragma unroll
    for (int k = 0; k < 5; ++k) {
        float p = y * p2w[k * 64 + lane];
        #pragma unroll
        for (int off = 32; off >= 1; off >>= 1) p += __shfl_xor(p, off);
        o5[k] = p;
    }
    if (lane == 0) {
        #pragma unroll
        for (int k = 0; k < 5; ++k) out[n * 5 + k] = o5[k] + p2b[k];
    }
}

// =====================================================================
extern "C" void kernel_launch(void* const* d_in, const int* in_sizes, int n_in,
                              void* d_out, int out_size, void* d_ws, size_t ws_size,
                              hipStream_t stream)
{
    const float* x   = (const float*)d_in[0];
    const float* c1w = (const float*)d_in[1];
    const float* c1b = (const float*)d_in[2];
    const float* b1s = (const float*)d_in[3];
    const float* b1b = (const float*)d_in[4];
    const float* b1m = (const float*)d_in[5];
    const float* b1v = (const float*)d_in[6];
    const float* c2w = (const float*)d_in[7];
    const float* c2b = (const float*)d_in[8];
    const float* b2s = (const float*)d_in[9];
    const float* b2b = (const float*)d_in[10];
    const float* b2m = (const float*)d_in[11];
    const float* b2v = (const float*)d_in[12];
    const float* c3w = (const float*)d_in[13];
    const float* c3b = (const float*)d_in[14];
    const float* b3s = (const float*)d_in[15];
    const float* b3b = (const float*)d_in[16];
    const float* b3m = (const float*)d_in[17];
    const float* b3v = (const float*)d_in[18];
    const float* prw = (const float*)d_in[19];
    const float* prb = (const float*)d_in[20];
    const float* qw  = (const float*)d_in[21];
    const float* p1w = (const float*)d_in[22];
    const float* p1b = (const float*)d_in[23];
    const float* p2w = (const float*)d_in[24];
    const float* p2b = (const float*)d_in[25];

    float* buf1   = (float*)d_ws;                              // NHWC (256,56,56,32)
    float* buf2   = buf1 + (size_t)256 * 3136 * 32;            // NHWC (256,28,28,64)
    float* buf3   = (float*)d_ws;                              // reuse: NHWC (256,14,14,128)
    float* pooled = buf3 + (size_t)256 * 196 * 128;            // (256,512)
    float* outp   = (float*)d_out;

    // conv1: NSB=1568, NOCG=4 -> grid 6272
    hipLaunchKernelGGL(conv1_bn_relu, dim3(1568 * 4), dim3(256), 0, stream,
                       x, c1w, c1b, b1s, b1b, b1m, b1v, buf1);

    // conv2: 32->64, 56->28.  NSB = 128*784/256 = 392 (%8==0), NOCG = 64/16 = 4
    hipLaunchKernelGGL((conv3x3_bn_relu_nhwc<32, 56, 56, 64, 28, 28, 392, 392, 4>),
                       dim3(392 * 4), dim3(256), 0, stream,
                       buf1, c2w, c2b, b2s, b2b, b2m, b2v, buf2);

    // conv3: 64->128, 28->14.  NSB = 128*196/256 = 98 -> NSBP=104, NOCG = 8
    hipLaunchKernelGGL((conv3x3_bn_relu_nhwc<64, 28, 28, 128, 14, 14, 98, 104, 8>),
                       dim3(104 * 8), dim3(256), 0, stream,
                       buf2, c3w, c3b, b3s, b3b, b3m, b3v, buf3);

    // pool: NHWC (256,14,14,128) -> (256,512) reference order
    hipLaunchKernelGGL(pool_kernel, dim3(131072 / 256), dim3(256), 0, stream,
                       buf3, pooled);

    // head: one wave per image
    hipLaunchKernelGGL(head_kernel, dim3(256), dim3(64), 0, stream,
                       pooled, prw, prb, qw, p1w, p1b, p2w, p2b, outp);
}